// Round 11
// baseline (341.933 us; speedup 1.0000x reference)
//
#include <hip/hip_runtime.h>

#define Bsz 8
#define Tn  2048
#define Cn  1024
#define Hn  16
#define Sn  64
#define Mn  (Bsz * Tn)   // 16384
#define NC  32
#define LCH (Tn / NC)    // 64
#define Kd  1024
#define NKT (Kd / 64)    // 16 K-tiles of 64

typedef __attribute__((ext_vector_type(8))) short bf16x8;
typedef __attribute__((ext_vector_type(4))) float f32x4;

__device__ __forceinline__ unsigned short f2bf(float f) {
  union { float f; unsigned int u; } v;
  v.f = f;
  unsigned int r = (v.u + 0x7FFFu + ((v.u >> 16) & 1u)) >> 16;
  return (unsigned short)r;
}
__device__ __forceinline__ float bf2f(unsigned short u) {
  union { unsigned int u; float f; } v;
  v.u = ((unsigned int)u) << 16;
  return v.f;
}

// ---------------- weight fp32 -> bf16 ----------------
__global__ void wconv_kernel(const float* __restrict__ Wk, const float* __restrict__ Wv,
                             const float* __restrict__ Wr, const float* __restrict__ Wo,
                             unsigned short* __restrict__ out) {
  int i = blockIdx.x * blockDim.x + threadIdx.x;
  int which = i >> 18;
  int off = (i & 0x3FFFF) * 4;
  const float* src = which == 0 ? Wk : which == 1 ? Wv : which == 2 ? Wr : Wo;
  float4 f = *(const float4*)(src + off);
  ushort4 o;
  o.x = f2bf(f.x); o.y = f2bf(f.y); o.z = f2bf(f.z); o.w = f2bf(f.w);
  *(ushort4*)(out + (size_t)which * (Cn * Cn) + off) = o;
}

// ---------------- fused time-shift mix ----------------
__global__ void mix3_kernel(const float* __restrict__ x,
                            const float* __restrict__ tmk, const float* __restrict__ tmv,
                            const float* __restrict__ tmr,
                            unsigned short* __restrict__ ok, unsigned short* __restrict__ ov,
                            unsigned short* __restrict__ orr) {
  int idx = blockIdx.x * blockDim.x + threadIdx.x;
  int c4 = idx & (Cn / 4 - 1);
  int bt = idx >> 8;
  int t = bt & (Tn - 1);
  size_t base = (size_t)bt * Cn + c4 * 4;
  float4 xv = *(const float4*)(x + base);
  float4 xxv = {0.f, 0.f, 0.f, 0.f};
  if (t != 0) xxv = *(const float4*)(x + base - Cn);
  float4 dx = {xv.x - xxv.x, xv.y - xxv.y, xv.z - xxv.z, xv.w - xxv.w};
  float4 tk = *(const float4*)(tmk + c4 * 4);
  float4 tv = *(const float4*)(tmv + c4 * 4);
  float4 tr = *(const float4*)(tmr + c4 * 4);
  ushort4 a, b, c;
  a.x = f2bf(xxv.x + tk.x * dx.x); a.y = f2bf(xxv.y + tk.y * dx.y);
  a.z = f2bf(xxv.z + tk.z * dx.z); a.w = f2bf(xxv.w + tk.w * dx.w);
  b.x = f2bf(xxv.x + tv.x * dx.x); b.y = f2bf(xxv.y + tv.y * dx.y);
  b.z = f2bf(xxv.z + tv.z * dx.z); b.w = f2bf(xxv.w + tv.w * dx.w);
  c.x = f2bf(xxv.x + tr.x * dx.x); c.y = f2bf(xxv.y + tr.y * dx.y);
  c.z = f2bf(xxv.z + tr.z * dx.z); c.w = f2bf(xxv.w + tr.w * dx.w);
  *(ushort4*)(ok + base) = a;
  *(ushort4*)(ov + base) = b;
  *(ushort4*)(orr + base) = c;
}

// ---------------- 256x256 GEMM core: 1 barrier + 1 counted vmcnt per K-tile ----------------
// C[m,n] = sum_k A[m,k]*Bt[n,k]; K = 1024.
// LDS dbuf x { A 256x64 (32KB) | B 256x64 (32KB) } = 128KB.
// Granule (r,c): physical slot = c ^ (r&7), byte = r*128 + slot*16 (conflict-free frag
// reads, proven R6). Staging slab = 8 rows per wave-gload (wave-uniform LDS base +
// lane*16, per HW rule); per-lane source carries the inverse swizzle (proven R9/R10).
// Schedule per kt (counted lookahead, R3-style but 1 barrier):
//   issue 4 slabs (A01,B01 of kt+1) -> vmcnt(4) drains exactly kt's 8 slabs
//   -> barrier -> compute KS=0 (compiler-scheduled) -> issue 4 slabs (A23,B23 of kt+1)
//   -> compute KS=1. WAR on kt+1's dbuf: its last readers (kt-1) finished before this
//   kt's barrier (program order + barrier chain). Ledger: entry 8 outstanding (all kt),
//   +4 = 12, drain to 4 (kt+1 grp0); mid-body +4 = 8 = entry invariant. Last kt: vmcnt(0).
__device__ __forceinline__ void gload_lds16(const void* g, void* l) {
  __builtin_amdgcn_global_load_lds((const __attribute__((address_space(1))) void*)g,
                                   (__attribute__((address_space(3))) void*)l, 16, 0, 0);
}

#define LDA(dst, H, KS)                                                            \
  _Pragma("unroll") for (int mi4 = 0; mi4 < 4; ++mi4) {                            \
    const int row = wm * 128 + (H) * 64 + mi4 * 16 + l15;                          \
    dst[mi4] = *(const bf16x8*)(ldsc + dbase + row * 128 +                         \
                                ((((KS) * 4 + lg) ^ (row & 7)) << 4));             \
  }
#define LDB(dst, KS)                                                               \
  _Pragma("unroll") for (int nj = 0; nj < 4; ++nj) {                               \
    const int row = wn * 64 + nj * 16 + l15;                                       \
    dst[nj] = *(const bf16x8*)(ldsc + dbase + 32768 + row * 128 +                  \
                               ((((KS) * 4 + lg) ^ (row & 7)) << 4));              \
  }
#define MFMA16(H, AV, BV)                                                          \
  _Pragma("unroll") for (int mi4 = 0; mi4 < 4; ++mi4)                              \
    _Pragma("unroll") for (int nj = 0; nj < 4; ++nj)                               \
      acc[(H) * 4 + mi4][nj] = __builtin_amdgcn_mfma_f32_16x16x32_bf16(            \
          AV[mi4], BV[nj], acc[(H) * 4 + mi4][nj], 0, 0, 0);

template <bool OUTBF16>
__device__ __forceinline__ void gemm_core(const unsigned short* __restrict__ Ag,
                                          const unsigned short* __restrict__ Bg,
                                          void* __restrict__ Cm,  // pre-offset to (m0,n0)
                                          char* ldsc) {
  const int tid = threadIdx.x;
  const int wid = tid >> 6, lane = tid & 63;
  const int wm = wid >> 2, wn = wid & 3;
  const int l15 = lane & 15, lg = lane >> 4;

  // stage one 8-row slab (1KB): wave-uniform LDS dest, inverse-swizzled source
  auto stageS = [&](const unsigned short* gbase, int ktt, int band, int Loff) {
    const int r = band * 64 + wid * 8 + (lane >> 3);
    const int c = (lane & 7) ^ (r & 7);
    gload_lds16(gbase + (size_t)r * Kd + ktt * 64 + c * 8,
                ldsc + Loff + (band * 64 + wid * 8) * 128 + lane * 16);
  };

  f32x4 acc[8][4] = {};

  // prologue: all 8 slabs of kt0 into buf0
#pragma unroll
  for (int band = 0; band < 4; ++band) stageS(Ag, 0, band, 0);
#pragma unroll
  for (int band = 0; band < 4; ++band) stageS(Bg, 0, band, 32768);

#pragma unroll 2
  for (int kt = 0; kt < NKT; ++kt) {
    const int dbase = (kt & 1) << 16;
    const int nd = dbase ^ 65536;
    const bool st = (kt + 1 < NKT);

    if (st) {  // group 0 of kt+1: A bands 0,1 + B bands 0,1
      stageS(Ag, kt + 1, 0, nd);
      stageS(Ag, kt + 1, 1, nd);
      stageS(Bg, kt + 1, 0, nd + 32768);
      stageS(Bg, kt + 1, 1, nd + 32768);
      asm volatile("s_waitcnt vmcnt(4)" ::: "memory");  // drains all 8 of kt
    } else {
      asm volatile("s_waitcnt vmcnt(0)" ::: "memory");
    }
    __builtin_amdgcn_s_barrier();
    __builtin_amdgcn_sched_barrier(0);

    // KS=0 (compiler-scheduled reads + MFMA)
    {
      bf16x8 a0[4], a1[4], b0[4];
      LDA(a0, 0, 0)
      LDA(a1, 1, 0)
      LDB(b0, 0)
      __builtin_amdgcn_s_setprio(1);
      MFMA16(0, a0, b0)
      MFMA16(1, a1, b0)
      __builtin_amdgcn_s_setprio(0);
    }
    if (st) {  // group 1 of kt+1: A bands 2,3 + B bands 2,3
      stageS(Ag, kt + 1, 2, nd);
      stageS(Ag, kt + 1, 3, nd);
      stageS(Bg, kt + 1, 2, nd + 32768);
      stageS(Bg, kt + 1, 3, nd + 32768);
    }
    // KS=1
    {
      bf16x8 a2[4], a3[4], b1[4];
      LDA(a2, 0, 1)
      LDA(a3, 1, 1)
      LDB(b1, 1)
      __builtin_amdgcn_s_setprio(1);
      MFMA16(0, a2, b1)
      MFMA16(1, a3, b1)
      __builtin_amdgcn_s_setprio(0);
    }
  }

  if (OUTBF16) {
    __syncthreads();  // all waves done reading LDS before reuse as transpose buffer
    char* tb = ldsc + wid * 16384;
#pragma unroll
    for (int mi = 0; mi < 8; ++mi)
#pragma unroll
      for (int nj = 0; nj < 4; ++nj)
#pragma unroll
        for (int rr = 0; rr < 4; ++rr) {
          const int row = mi * 16 + lg * 4 + rr;
          const int col = nj * 16 + l15;
          *(unsigned short*)(tb + row * 128 + ((col * 2) ^ ((row & 7) << 4))) =
              f2bf(acc[mi][nj][rr]);
        }
    asm volatile("s_waitcnt lgkmcnt(0)" ::: "memory");
    __builtin_amdgcn_sched_barrier(0);
    const int orl = lane >> 3, och = lane & 7;
#pragma unroll
    for (int it = 0; it < 16; ++it) {
      const int row = it * 8 + orl;
      uint4 vv = *(const uint4*)(tb + row * 128 + ((och * 16) ^ ((row & 7) << 4)));
      const int gr = wm * 128 + row;
      const int gc = wn * 64 + och * 8;
      *(uint4*)((unsigned short*)Cm + (size_t)gr * Cn + gc) = vv;
    }
  } else {
#pragma unroll
    for (int mi = 0; mi < 8; ++mi)
#pragma unroll
      for (int nj = 0; nj < 4; ++nj)
#pragma unroll
        for (int rr = 0; rr < 4; ++rr) {
          const int row = wm * 128 + mi * 16 + lg * 4 + rr;
          const int col = wn * 64 + nj * 16 + l15;
          ((float*)Cm)[(size_t)row * Cn + col] = acc[mi][nj][rr];
        }
  }
}

// fused 3-projection GEMM: grid 768 = 64 mt x (3 proj x 4 nt), nt-major for L2 A-reuse
__global__ __launch_bounds__(512, 2) void gemmF(const unsigned short* __restrict__ xk,
                                                const unsigned short* __restrict__ xv,
                                                const unsigned short* __restrict__ xr,
                                                const unsigned short* __restrict__ wbf,
                                                unsigned short* __restrict__ ck,
                                                unsigned short* __restrict__ cv,
                                                unsigned short* __restrict__ cr) {
  __shared__ unsigned short lds[65536];
  int bid = ((int)blockIdx.x & 7) * 96 + ((int)blockIdx.x >> 3);  // XCD-bijective (768%8==0)
  const int nt = bid & 3;
  const int g = bid >> 2;
  const int proj = g >> 6;
  const int mt = g & 63;
  const unsigned short* A = proj == 0 ? xk : proj == 1 ? xv : xr;
  unsigned short* C = proj == 0 ? ck : proj == 1 ? cv : cr;
  const unsigned short* W = wbf + (size_t)proj * Cn * Cn;
  gemm_core<true>(A + (size_t)mt * 256 * Kd, W + (size_t)nt * 256 * Kd,
                  C + (size_t)mt * 256 * Cn + nt * 256, (char*)lds);
}

// output projection GEMM: grid 256, fp32 out
__global__ __launch_bounds__(512, 2) void gemmO(const unsigned short* __restrict__ A,
                                                const unsigned short* __restrict__ W,
                                                float* __restrict__ C) {
  __shared__ unsigned short lds[65536];
  int bid = ((int)blockIdx.x & 7) * 32 + ((int)blockIdx.x >> 3);
  const int nt = bid & 3;
  const int mt = bid >> 2;
  gemm_core<false>(A + (size_t)mt * 256 * Kd, W + (size_t)nt * 256 * Kd,
                   C + (size_t)mt * 256 * Cn + nt * 256, (char*)lds);
}

// ---------------- chunked scan (bf16 in/out, fp32 state) ----------------
__global__ void scan_phase1(const unsigned short* __restrict__ k,
                            const unsigned short* __restrict__ v,
                            const float* __restrict__ td, float* __restrict__ cs) {
  int blk = blockIdx.x;
  int c = blk & (NC - 1);
  int bh = blk >> 5;
  int b = bh >> 4;
  int h = bh & 15;
  int s = threadIdx.x;
  float decay = expf(td[h * Sn + s]);
  size_t base = ((size_t)(b * Tn + c * LCH)) * Cn + h * Sn + s;
  float st = 0.f;
#pragma unroll 8
  for (int i = 0; i < LCH; ++i) {
    float kv = bf2f(k[base]) * bf2f(v[base]);
    st = kv + decay * st;
    base += Cn;
  }
  cs[(size_t)blk * Sn + s] = st;
}

__global__ void scan_phase2(const float* __restrict__ td, float* __restrict__ cs) {
  int bh = blockIdx.x;
  int h = bh & 15;
  int s = threadIdx.x;
  float dL = expf(td[h * Sn + s] * (float)LCH);
  float carry = 0.f;
  for (int c = 0; c < NC; ++c) {
    size_t idx = ((size_t)bh * NC + c) * Sn + s;
    float sc = cs[idx];
    cs[idx] = carry;
    carry = sc + dL * carry;
  }
}

__global__ void scan_phase3(const unsigned short* __restrict__ k,
                            const unsigned short* __restrict__ v,
                            const unsigned short* __restrict__ r,
                            const float* __restrict__ td, const float* __restrict__ tf,
                            const float* __restrict__ cs,
                            unsigned short* __restrict__ out) {
  int blk = blockIdx.x;
  int c = blk & (NC - 1);
  int bh = blk >> 5;
  int b = bh >> 4;
  int h = bh & 15;
  int s = threadIdx.x;
  float decay = expf(td[h * Sn + s]);
  float first = tf[h * Sn + s];
  float st = cs[(size_t)blk * Sn + s];
  size_t base = ((size_t)(b * Tn + c * LCH)) * Cn + h * Sn + s;
#pragma unroll 8
  for (int i = 0; i < LCH; ++i) {
    float kv = bf2f(k[base]) * bf2f(v[base]);
    st = kv + decay * st;
    out[base] = f2bf(bf2f(r[base]) * (first * kv + st));
    base += Cn;
  }
}

// ---------------- layernorm (bf16 in) -> bf16 ----------------
__global__ __launch_bounds__(256) void ln_kernel(const unsigned short* __restrict__ in,
                                                 const float* __restrict__ g,
                                                 const float* __restrict__ bb,
                                                 unsigned short* __restrict__ out) {
  int row = blockIdx.x;
  int tid = threadIdx.x;
  size_t base = (size_t)row * Cn + tid * 4;
  ushort4 uv = *(const ushort4*)(in + base);
  float4 xv = {bf2f(uv.x), bf2f(uv.y), bf2f(uv.z), bf2f(uv.w)};
  float sum = xv.x + xv.y + xv.z + xv.w;
  float ss = xv.x * xv.x + xv.y * xv.y + xv.z * xv.z + xv.w * xv.w;
#pragma unroll
  for (int off = 32; off >= 1; off >>= 1) {
    sum += __shfl_down(sum, off, 64);
    ss += __shfl_down(ss, off, 64);
  }
  __shared__ float s1[4], s2[4];
  if ((tid & 63) == 0) { s1[tid >> 6] = sum; s2[tid >> 6] = ss; }
  __syncthreads();
  sum = s1[0] + s1[1] + s1[2] + s1[3];
  ss = s2[0] + s2[1] + s2[2] + s2[3];
  float mu = sum * (1.f / Cn);
  float var = ss * (1.f / Cn) - mu * mu;
  float rstd = rsqrtf(var + 1e-5f);
  float4 gv = *(const float4*)(g + tid * 4);
  float4 bv = *(const float4*)(bb + tid * 4);
  ushort4 o;
  o.x = f2bf((xv.x - mu) * rstd * gv.x + bv.x);
  o.y = f2bf((xv.y - mu) * rstd * gv.y + bv.y);
  o.z = f2bf((xv.z - mu) * rstd * gv.z + bv.z);
  o.w = f2bf((xv.w - mu) * rstd * gv.w + bv.w);
  *(ushort4*)(out + base) = o;
}

extern "C" void kernel_launch(void* const* d_in, const int* in_sizes, int n_in,
                              void* d_out, int out_size, void* d_ws, size_t ws_size,
                              hipStream_t stream) {
  const float* x   = (const float*)d_in[0];
  const float* tmk = (const float*)d_in[1];
  const float* tmv = (const float*)d_in[2];
  const float* tmr = (const float*)d_in[3];
  const float* td  = (const float*)d_in[4];
  const float* tf  = (const float*)d_in[5];
  const float* Wk  = (const float*)d_in[6];
  const float* Wv  = (const float*)d_in[7];
  const float* Wr  = (const float*)d_in[8];
  const float* Wo  = (const float*)d_in[9];
  const float* lng = (const float*)d_in[10];
  const float* lnb = (const float*)d_in[11];
  float* out = (float*)d_out;

  char* ws = (char*)d_ws;
  const size_t MB = 1024 * 1024;
  unsigned short* wbf  = (unsigned short*)(ws);              // 8 MB (4 weights bf16)
  unsigned short* xk   = (unsigned short*)(ws + 8 * MB);     // 32 MB
  unsigned short* xv_  = (unsigned short*)(ws + 40 * MB);    // 32 MB
  unsigned short* xr   = (unsigned short*)(ws + 72 * MB);    // 32 MB
  unsigned short* bufK = (unsigned short*)(ws + 104 * MB);   // 32 MB
  unsigned short* bufV = (unsigned short*)(ws + 136 * MB);   // 32 MB
  unsigned short* bufR = (unsigned short*)(ws + 168 * MB);   // 32 MB
  unsigned short* preLN = xk;                                // reuse
  unsigned short* lnout = xv_;                               // reuse
  float* chunkS = (float*)(ws + 200 * MB);                   // 1 MB

  const int mix_grid = Mn * (Cn / 4) / 256;  // 16384

  wconv_kernel<<<4 * Cn * Cn / 4 / 256, 256, 0, stream>>>(Wk, Wv, Wr, Wo, wbf);
  mix3_kernel<<<mix_grid, 256, 0, stream>>>(x, tmk, tmv, tmr, xk, xv_, xr);

  gemmF<<<768, 512, 0, stream>>>(xk, xv_, xr, wbf, bufK, bufV, bufR);

  scan_phase1<<<Bsz * Hn * NC, 64, 0, stream>>>(bufK, bufV, td, chunkS);
  scan_phase2<<<Bsz * Hn, 64, 0, stream>>>(td, chunkS);
  scan_phase3<<<Bsz * Hn * NC, 64, 0, stream>>>(bufK, bufV, bufR, td, tf, chunkS, preLN);

  ln_kernel<<<Mn, 256, 0, stream>>>(preLN, lng, lnb, lnout);

  gemmO<<<256, 512, 0, stream>>>(lnout, wbf + 3 * (size_t)Cn * Cn, out);

  (void)in_sizes; (void)n_in; (void)out_size; (void)ws_size;
}